// Round 3
// baseline (445.005 us; speedup 1.0000x reference)
//
#include <hip/hip_runtime.h>
#include <hip/hip_bf16.h>

#define BB 8
#define CC 64
#define HH 256
#define WW 256

__device__ __forceinline__ unsigned short f2bf(float f) {
    __hip_bfloat16 h = __float2bfloat16(f);   // RNE
    return *reinterpret_cast<unsigned short*>(&h);
}
__device__ __forceinline__ float bf2f(unsigned short u) {
    unsigned int v = ((unsigned int)u) << 16;
    float r;
    __builtin_memcpy(&r, &v, 4);
    return r;
}
__device__ __forceinline__ float bflo(unsigned int u) {   // low ushort -> float
    unsigned int v = u << 16;
    float r; __builtin_memcpy(&r, &v, 4); return r;
}
__device__ __forceinline__ float bfhi(unsigned int u) {   // high ushort -> float
    unsigned int v = u & 0xffff0000u;
    float r; __builtin_memcpy(&r, &v, 4); return r;
}

// ---------------------------------------------------------------------------
// K1: fused 5x5 depthwise (pad 2) + 1x21 horizontal depthwise (pad 10).
// LDS-pipe-bound (round-2 counters) -> reduce LDS instrs/output:
// 32-row strip, 512 threads, thread = 2 rows x 8 cols.
// Per thread: 24 b128 reads for 16 px of 5x5 (rows shared), 16 b128 for h-conv.
// LDS wave-ops/row: 12.3 vs 24.8 in round-2.
// ---------------------------------------------------------------------------
__global__ __launch_bounds__(512) void k1_local_h(
        const float* __restrict__ x, const float* __restrict__ lw,
        const float* __restrict__ hw, unsigned short* __restrict__ a2out) {
    const int strip = blockIdx.x;          // 0..7
    const int bc    = blockIdx.y;          // 0..511
    const int c     = bc & (CC - 1);
    const int y0    = strip * 32;
    const int tid   = threadIdx.x;

    // xs4[rr][g]: x row (y0-2+rr), group g covers gx = 4g-4..4g-1 (g 0..65)
    __shared__ float4 xs4[36][66];         // 38016 B
    // a1_4[r][G]: 5x5 out row (y0+r), G covers xc = 4G-12..4G-9 (G 0..69)
    // valid xc 0..255 -> G 3..66; G 0..2 / 67..69 zero pad (h pad 10)
    __shared__ float4 a1_4[32][70];        // 35840 B   (total 73856 -> 2 blk/CU)

    const float* xbase = x + (size_t)bc * (HH * WW);

    // zero a1 pads: 32 rows x {0,1,2,67,68,69}
    if (tid < 192) {
        int rr = tid / 6, g = tid % 6;
        a1_4[rr][g < 3 ? g : 64 + g] = make_float4(0.f, 0.f, 0.f, 0.f);
    }
    // stage x rows y0-2 .. y0+33 (zero halo)
    for (int i = tid; i < 36 * 66; i += 512) {
        int rr = i / 66, g = i - rr * 66;
        int gy = y0 - 2 + rr;
        float4 v = make_float4(0.f, 0.f, 0.f, 0.f);
        if (gy >= 0 && gy < HH && g >= 1 && g <= 64)
            v = *reinterpret_cast<const float4*>(xbase + (size_t)gy * WW + 4 * (g - 1));
        xs4[rr][g] = v;
    }
    __syncthreads();

    const int cg = tid & 31;               // 8-col group: cols 8cg..8cg+7
    const int rp = tid >> 5;               // row pair: rows y0+2rp, y0+2rp+1
    const float* lwc = lw + c * 25;        // block-uniform -> s_load

    float acc0[8], acc1[8];
    #pragma unroll
    for (int j = 0; j < 8; ++j) { acc0[j] = 0.f; acc1[j] = 0.f; }

    // 6 xs rows feed both output rows (5 each, offset 1).
    // f idx: xc = 8cg-4+f; tap xc = 8cg+j+kx-2 -> f = j+kx+2 in [2,13]
    #pragma unroll
    for (int t = 0; t < 6; ++t) {
        float4 g0 = xs4[2 * rp + t][2 * cg + 0];
        float4 g1 = xs4[2 * rp + t][2 * cg + 1];
        float4 g2 = xs4[2 * rp + t][2 * cg + 2];
        float4 g3 = xs4[2 * rp + t][2 * cg + 3];
        float f[16] = {g0.x, g0.y, g0.z, g0.w, g1.x, g1.y, g1.z, g1.w,
                       g2.x, g2.y, g2.z, g2.w, g3.x, g3.y, g3.z, g3.w};
        if (t < 5) {
            #pragma unroll
            for (int kx = 0; kx < 5; ++kx) {
                float wv = lwc[t * 5 + kx];
                #pragma unroll
                for (int j = 0; j < 8; ++j)
                    acc0[j] = fmaf(wv, f[j + kx + 2], acc0[j]);
            }
        }
        if (t >= 1) {
            #pragma unroll
            for (int kx = 0; kx < 5; ++kx) {
                float wv = lwc[(t - 1) * 5 + kx];
                #pragma unroll
                for (int j = 0; j < 8; ++j)
                    acc1[j] = fmaf(wv, f[j + kx + 2], acc1[j]);
            }
        }
    }
    // out cols 8cg..8cg+7 -> groups 2cg+3, 2cg+4
    a1_4[2 * rp + 0][2 * cg + 3] = make_float4(acc0[0], acc0[1], acc0[2], acc0[3]);
    a1_4[2 * rp + 0][2 * cg + 4] = make_float4(acc0[4], acc0[5], acc0[6], acc0[7]);
    a1_4[2 * rp + 1][2 * cg + 3] = make_float4(acc1[0], acc1[1], acc1[2], acc1[3]);
    a1_4[2 * rp + 1][2 * cg + 4] = make_float4(acc1[4], acc1[5], acc1[6], acc1[7]);
    __syncthreads();

    const float* hwc = hw + c * 21;
    #pragma unroll
    for (int row = 0; row < 2; ++row) {
        // window: groups 2cg..2cg+7; f = 4t+u maps xc = 8cg+f-12;
        // tap xc = 8cg+j+k-10 -> f = j+k+2 in [2,29]
        float fw[32];
        #pragma unroll
        for (int t2 = 0; t2 < 8; ++t2) {
            float4 g = a1_4[2 * rp + row][2 * cg + t2];
            fw[4 * t2 + 0] = g.x; fw[4 * t2 + 1] = g.y;
            fw[4 * t2 + 2] = g.z; fw[4 * t2 + 3] = g.w;
        }
        float o[8];
        #pragma unroll
        for (int j = 0; j < 8; ++j) o[j] = 0.f;
        #pragma unroll
        for (int k = 0; k < 21; ++k) {
            float wv = hwc[k];
            #pragma unroll
            for (int j = 0; j < 8; ++j)
                o[j] = fmaf(wv, fw[j + k + 2], o[j]);
        }
        unsigned short* dst = a2out + (size_t)(bc * HH + y0 + 2 * rp + row) * WW + 8 * cg;
        uint4 pk;
        pk.x = (unsigned)f2bf(o[0]) | ((unsigned)f2bf(o[1]) << 16);
        pk.y = (unsigned)f2bf(o[2]) | ((unsigned)f2bf(o[3]) << 16);
        pk.z = (unsigned)f2bf(o[4]) | ((unsigned)f2bf(o[5]) << 16);
        pk.w = (unsigned)f2bf(o[6]) | ((unsigned)f2bf(o[7]) << 16);
        *reinterpret_cast<uint4*>(dst) = pk;
    }
}

// ---------------------------------------------------------------------------
// K2a: 21x1 vertical depthwise (pad 10), gather through LDS.
// Occupancy fix: tile 84 rows x 128 cols bf16 = 21.5 KB -> 7 blocks/CU
// (28 waves) vs round-2's 43 KB / 12 waves.  256 threads: thread = 4 rows x
// 8 cols, 8 named accumulators per row (no runtime-indexed arrays).
// ---------------------------------------------------------------------------
__global__ __launch_bounds__(256) void k2a_v(
        const unsigned short* __restrict__ a2, const float* __restrict__ vw,
        unsigned short* __restrict__ a3) {
    const int bx    = blockIdx.x;          // 0..7
    const int strip = bx >> 1;             // 0..3 -> y0
    const int x0    = (bx & 1) * 128;      // col half
    const int bc    = blockIdx.y;
    const int c     = bc & (CC - 1);
    const int y0    = strip * 64;
    const int tid   = threadIdx.x;

    __shared__ unsigned short lds[84][128];   // 21504 B

    const unsigned short* sbase = a2 + (size_t)bc * (HH * WW) + x0;
    // stage rows y0-10 .. y0+73 (zero halo): 84*16 uint4 chunks
    for (int i = tid; i < 84 * 16; i += 256) {
        int row = i >> 4, g = i & 15;
        int gy = y0 - 10 + row;
        uint4 v = make_uint4(0u, 0u, 0u, 0u);
        if (gy >= 0 && gy < HH)
            v = *reinterpret_cast<const uint4*>(sbase + (size_t)gy * WW + g * 8);
        *reinterpret_cast<uint4*>(&lds[row][g * 8]) = v;
    }
    __syncthreads();

    const float* vwc = vw + c * 21;        // block-uniform -> s_load
    float w[21];
    #pragma unroll
    for (int k = 0; k < 21; ++k) w[k] = vwc[k];

    const int cg = tid & 15;               // cols x0+8cg..x0+8cg+7
    const int rg = tid >> 4;               // rows y0+4rg..y0+4rg+3
    unsigned short* dst = a3 + (size_t)bc * (HH * WW)
                        + (size_t)(y0 + rg * 4) * WW + x0 + cg * 8;

    #pragma unroll 1
    for (int i = 0; i < 4; ++i) {
        float s0 = 0.f, s1 = 0.f, s2 = 0.f, s3 = 0.f;
        float s4 = 0.f, s5 = 0.f, s6 = 0.f, s7 = 0.f;
        #pragma unroll
        for (int k = 0; k < 21; ++k) {
            // out[y0+4rg+i] += w[k] * in[y0+4rg+i+k-10]; staged row = 4rg+i+k
            uint4 u = *reinterpret_cast<const uint4*>(&lds[rg * 4 + i + k][cg * 8]);
            float wk = w[k];
            s0 = fmaf(wk, bflo(u.x), s0); s1 = fmaf(wk, bfhi(u.x), s1);
            s2 = fmaf(wk, bflo(u.y), s2); s3 = fmaf(wk, bfhi(u.y), s3);
            s4 = fmaf(wk, bflo(u.z), s4); s5 = fmaf(wk, bfhi(u.z), s5);
            s6 = fmaf(wk, bflo(u.w), s6); s7 = fmaf(wk, bfhi(u.w), s7);
        }
        uint4 o;
        o.x = (unsigned int)f2bf(s0) | ((unsigned int)f2bf(s1) << 16);
        o.y = (unsigned int)f2bf(s2) | ((unsigned int)f2bf(s3) << 16);
        o.z = (unsigned int)f2bf(s4) | ((unsigned int)f2bf(s5) << 16);
        o.w = (unsigned int)f2bf(s6) | ((unsigned int)f2bf(s7) << 16);
        *reinterpret_cast<uint4*>(dst + (size_t)i * WW) = o;
    }
}

// ---------------------------------------------------------------------------
// K2b: 1x1 pointwise (64x64) + BN + sigmoid gate.
// SMEM fix: walk weights in ci-chunks of 4 so each uniform weight access is a
// float4 -> s_load_dwordx4 (256 SMEM instrs/wave vs 4096 s_load_dword).
// Accumulation order over ci unchanged -> bitwise-identical result.
// ---------------------------------------------------------------------------
__global__ __launch_bounds__(256) void k2b_pw(
        const unsigned short* __restrict__ a3, const float* __restrict__ x,
        const float* __restrict__ pw, const float* __restrict__ gamma,
        const float* __restrict__ beta, const float* __restrict__ mean,
        const float* __restrict__ var, float* __restrict__ out) {
    const int y   = blockIdx.x;
    const int b   = blockIdx.y;
    const int tid = threadIdx.x;

    __shared__ unsigned short a3s[64][256];   // 32 KB

    const unsigned short* abase = a3 + ((size_t)b * CC * HH + y) * WW;
    for (int i = tid; i < 64 * 64; i += 256) {
        int ci = i >> 6, q = (i & 63) << 2;
        ushort4 v = *reinterpret_cast<const ushort4*>(abase + (size_t)ci * HH * WW + q);
        *reinterpret_cast<ushort4*>(&a3s[ci][q]) = v;
    }
    __syncthreads();

    const int wu = __builtin_amdgcn_readfirstlane(tid >> 6);  // wave-uniform co group
    const int l  = tid & 63;

    float acc[64];
    #pragma unroll
    for (int i = 0; i < 64; ++i) acc[i] = 0.f;

    const float* wbase = pw + (size_t)(wu * 16) * 64;

    #pragma unroll
    for (int ch = 0; ch < 16; ++ch) {
        ushort4 q0 = *reinterpret_cast<const ushort4*>(&a3s[4 * ch + 0][l << 2]);
        ushort4 q1 = *reinterpret_cast<const ushort4*>(&a3s[4 * ch + 1][l << 2]);
        ushort4 q2 = *reinterpret_cast<const ushort4*>(&a3s[4 * ch + 2][l << 2]);
        ushort4 q3 = *reinterpret_cast<const ushort4*>(&a3s[4 * ch + 3][l << 2]);
        float p0x = bf2f(q0.x), p0y = bf2f(q0.y), p0z = bf2f(q0.z), p0w = bf2f(q0.w);
        float p1x = bf2f(q1.x), p1y = bf2f(q1.y), p1z = bf2f(q1.z), p1w = bf2f(q1.w);
        float p2x = bf2f(q2.x), p2y = bf2f(q2.y), p2z = bf2f(q2.z), p2w = bf2f(q2.w);
        float p3x = bf2f(q3.x), p3y = bf2f(q3.y), p3z = bf2f(q3.z), p3w = bf2f(q3.w);
        #pragma unroll
        for (int j = 0; j < 16; ++j) {
            float4 w4 = *reinterpret_cast<const float4*>(wbase + (size_t)j * 64 + 4 * ch);
            acc[j * 4 + 0] = fmaf(w4.x, p0x, acc[j * 4 + 0]);
            acc[j * 4 + 0] = fmaf(w4.y, p1x, acc[j * 4 + 0]);
            acc[j * 4 + 0] = fmaf(w4.z, p2x, acc[j * 4 + 0]);
            acc[j * 4 + 0] = fmaf(w4.w, p3x, acc[j * 4 + 0]);
            acc[j * 4 + 1] = fmaf(w4.x, p0y, acc[j * 4 + 1]);
            acc[j * 4 + 1] = fmaf(w4.y, p1y, acc[j * 4 + 1]);
            acc[j * 4 + 1] = fmaf(w4.z, p2y, acc[j * 4 + 1]);
            acc[j * 4 + 1] = fmaf(w4.w, p3y, acc[j * 4 + 1]);
            acc[j * 4 + 2] = fmaf(w4.x, p0z, acc[j * 4 + 2]);
            acc[j * 4 + 2] = fmaf(w4.y, p1z, acc[j * 4 + 2]);
            acc[j * 4 + 2] = fmaf(w4.z, p2z, acc[j * 4 + 2]);
            acc[j * 4 + 2] = fmaf(w4.w, p3z, acc[j * 4 + 2]);
            acc[j * 4 + 3] = fmaf(w4.x, p0w, acc[j * 4 + 3]);
            acc[j * 4 + 3] = fmaf(w4.y, p1w, acc[j * 4 + 3]);
            acc[j * 4 + 3] = fmaf(w4.z, p2w, acc[j * 4 + 3]);
            acc[j * 4 + 3] = fmaf(w4.w, p3w, acc[j * 4 + 3]);
        }
    }

    #pragma unroll
    for (int j = 0; j < 16; ++j) {
        int co = wu * 16 + j;
        float inv = gamma[co] * rsqrtf(var[co] + 1e-5f);
        float sh  = beta[co] - mean[co] * inv;
        size_t off = (((size_t)b * CC + co) * HH + y) * WW + (l << 2);
        float4 xv = *reinterpret_cast<const float4*>(x + off);
        float4 r;
        float a;
        a = acc[j * 4 + 0] * inv + sh; r.x = xv.x / (1.f + __expf(-a));
        a = acc[j * 4 + 1] * inv + sh; r.y = xv.y / (1.f + __expf(-a));
        a = acc[j * 4 + 2] * inv + sh; r.z = xv.z / (1.f + __expf(-a));
        a = acc[j * 4 + 3] * inv + sh; r.w = xv.w / (1.f + __expf(-a));
        *reinterpret_cast<float4*>(out + off) = r;
    }
}

extern "C" void kernel_launch(void* const* d_in, const int* in_sizes, int n_in,
                              void* d_out, int out_size, void* d_ws, size_t ws_size,
                              hipStream_t stream) {
    const float* x     = (const float*)d_in[0];
    const float* lw    = (const float*)d_in[1];
    const float* hw    = (const float*)d_in[2];
    const float* vw    = (const float*)d_in[3];
    const float* pw    = (const float*)d_in[4];
    const float* gamma = (const float*)d_in[5];
    const float* beta  = (const float*)d_in[6];
    const float* mean  = (const float*)d_in[7];
    const float* var   = (const float*)d_in[8];
    float* out = (float*)d_out;

    // ws: attn2 (bf16) + attn3 (bf16) = 2 * 64 MiB = 128 MiB
    unsigned short* ws1 = (unsigned short*)d_ws;
    unsigned short* ws2 = ws1 + (size_t)BB * CC * HH * WW;

    k1_local_h<<<dim3(HH / 32, BB * CC), 512, 0, stream>>>(x, lw, hw, ws1);
    k2a_v<<<dim3(8, BB * CC), 256, 0, stream>>>(ws1, vw, ws2);
    k2b_pw<<<dim3(HH, BB), 256, 0, stream>>>(ws2, x, pw, gamma, beta, mean, var, out);
}

// Round 4
// 415.765 us; speedup vs baseline: 1.0703x; 1.0703x over previous
//
#include <hip/hip_runtime.h>
#include <hip/hip_bf16.h>

#define BB 8
#define CC 64
#define HH 256
#define WW 256

__device__ __forceinline__ unsigned short f2bf(float f) {
    __hip_bfloat16 h = __float2bfloat16(f);   // RNE
    return *reinterpret_cast<unsigned short*>(&h);
}
__device__ __forceinline__ float bf2f(unsigned short u) {
    unsigned int v = ((unsigned int)u) << 16;
    float r;
    __builtin_memcpy(&r, &v, 4);
    return r;
}
__device__ __forceinline__ float bflo(unsigned int u) {   // low ushort -> float
    unsigned int v = u << 16;
    float r; __builtin_memcpy(&r, &v, 4); return r;
}
__device__ __forceinline__ float bfhi(unsigned int u) {   // high ushort -> float
    unsigned int v = u & 0xffff0000u;
    float r; __builtin_memcpy(&r, &v, 4); return r;
}

// ---------------------------------------------------------------------------
// K1: fused 5x5 depthwise (pad 2) + 1x21 horizontal depthwise (pad 10).
// (unchanged from round 3)
// ---------------------------------------------------------------------------
__global__ __launch_bounds__(512) void k1_local_h(
        const float* __restrict__ x, const float* __restrict__ lw,
        const float* __restrict__ hw, unsigned short* __restrict__ a2out) {
    const int strip = blockIdx.x;          // 0..7
    const int bc    = blockIdx.y;          // 0..511
    const int c     = bc & (CC - 1);
    const int y0    = strip * 32;
    const int tid   = threadIdx.x;

    // xs4[rr][g]: x row (y0-2+rr), group g covers gx = 4g-4..4g-1 (g 0..65)
    __shared__ float4 xs4[36][66];         // 38016 B
    // a1_4[r][G]: 5x5 out row (y0+r), G covers xc = 4G-12..4G-9 (G 0..69)
    __shared__ float4 a1_4[32][70];        // 35840 B

    const float* xbase = x + (size_t)bc * (HH * WW);

    if (tid < 192) {
        int rr = tid / 6, g = tid % 6;
        a1_4[rr][g < 3 ? g : 64 + g] = make_float4(0.f, 0.f, 0.f, 0.f);
    }
    for (int i = tid; i < 36 * 66; i += 512) {
        int rr = i / 66, g = i - rr * 66;
        int gy = y0 - 2 + rr;
        float4 v = make_float4(0.f, 0.f, 0.f, 0.f);
        if (gy >= 0 && gy < HH && g >= 1 && g <= 64)
            v = *reinterpret_cast<const float4*>(xbase + (size_t)gy * WW + 4 * (g - 1));
        xs4[rr][g] = v;
    }
    __syncthreads();

    const int cg = tid & 31;               // 8-col group: cols 8cg..8cg+7
    const int rp = tid >> 5;               // row pair: rows y0+2rp, y0+2rp+1
    const float* lwc = lw + c * 25;        // block-uniform -> s_load

    float acc0[8], acc1[8];
    #pragma unroll
    for (int j = 0; j < 8; ++j) { acc0[j] = 0.f; acc1[j] = 0.f; }

    #pragma unroll
    for (int t = 0; t < 6; ++t) {
        float4 g0 = xs4[2 * rp + t][2 * cg + 0];
        float4 g1 = xs4[2 * rp + t][2 * cg + 1];
        float4 g2 = xs4[2 * rp + t][2 * cg + 2];
        float4 g3 = xs4[2 * rp + t][2 * cg + 3];
        float f[16] = {g0.x, g0.y, g0.z, g0.w, g1.x, g1.y, g1.z, g1.w,
                       g2.x, g2.y, g2.z, g2.w, g3.x, g3.y, g3.z, g3.w};
        if (t < 5) {
            #pragma unroll
            for (int kx = 0; kx < 5; ++kx) {
                float wv = lwc[t * 5 + kx];
                #pragma unroll
                for (int j = 0; j < 8; ++j)
                    acc0[j] = fmaf(wv, f[j + kx + 2], acc0[j]);
            }
        }
        if (t >= 1) {
            #pragma unroll
            for (int kx = 0; kx < 5; ++kx) {
                float wv = lwc[(t - 1) * 5 + kx];
                #pragma unroll
                for (int j = 0; j < 8; ++j)
                    acc1[j] = fmaf(wv, f[j + kx + 2], acc1[j]);
            }
        }
    }
    a1_4[2 * rp + 0][2 * cg + 3] = make_float4(acc0[0], acc0[1], acc0[2], acc0[3]);
    a1_4[2 * rp + 0][2 * cg + 4] = make_float4(acc0[4], acc0[5], acc0[6], acc0[7]);
    a1_4[2 * rp + 1][2 * cg + 3] = make_float4(acc1[0], acc1[1], acc1[2], acc1[3]);
    a1_4[2 * rp + 1][2 * cg + 4] = make_float4(acc1[4], acc1[5], acc1[6], acc1[7]);
    __syncthreads();

    const float* hwc = hw + c * 21;
    #pragma unroll
    for (int row = 0; row < 2; ++row) {
        float fw[32];
        #pragma unroll
        for (int t2 = 0; t2 < 8; ++t2) {
            float4 g = a1_4[2 * rp + row][2 * cg + t2];
            fw[4 * t2 + 0] = g.x; fw[4 * t2 + 1] = g.y;
            fw[4 * t2 + 2] = g.z; fw[4 * t2 + 3] = g.w;
        }
        float o[8];
        #pragma unroll
        for (int j = 0; j < 8; ++j) o[j] = 0.f;
        #pragma unroll
        for (int k = 0; k < 21; ++k) {
            float wv = hwc[k];
            #pragma unroll
            for (int j = 0; j < 8; ++j)
                o[j] = fmaf(wv, fw[j + k + 2], o[j]);
        }
        unsigned short* dst = a2out + (size_t)(bc * HH + y0 + 2 * rp + row) * WW + 8 * cg;
        uint4 pk;
        pk.x = (unsigned)f2bf(o[0]) | ((unsigned)f2bf(o[1]) << 16);
        pk.y = (unsigned)f2bf(o[2]) | ((unsigned)f2bf(o[3]) << 16);
        pk.z = (unsigned)f2bf(o[4]) | ((unsigned)f2bf(o[5]) << 16);
        pk.w = (unsigned)f2bf(o[6]) | ((unsigned)f2bf(o[7]) << 16);
        *reinterpret_cast<uint4*>(dst) = pk;
    }
}

// ---------------------------------------------------------------------------
// K2a: 21x1 vertical depthwise (pad 10), gather through LDS.
// (unchanged from round 3)
// ---------------------------------------------------------------------------
__global__ __launch_bounds__(256) void k2a_v(
        const unsigned short* __restrict__ a2, const float* __restrict__ vw,
        unsigned short* __restrict__ a3) {
    const int bx    = blockIdx.x;          // 0..7
    const int strip = bx >> 1;             // 0..3 -> y0
    const int x0    = (bx & 1) * 128;      // col half
    const int bc    = blockIdx.y;
    const int c     = bc & (CC - 1);
    const int y0    = strip * 64;
    const int tid   = threadIdx.x;

    __shared__ unsigned short lds[84][128];   // 21504 B

    const unsigned short* sbase = a2 + (size_t)bc * (HH * WW) + x0;
    for (int i = tid; i < 84 * 16; i += 256) {
        int row = i >> 4, g = i & 15;
        int gy = y0 - 10 + row;
        uint4 v = make_uint4(0u, 0u, 0u, 0u);
        if (gy >= 0 && gy < HH)
            v = *reinterpret_cast<const uint4*>(sbase + (size_t)gy * WW + g * 8);
        *reinterpret_cast<uint4*>(&lds[row][g * 8]) = v;
    }
    __syncthreads();

    const float* vwc = vw + c * 21;        // block-uniform -> s_load
    float w[21];
    #pragma unroll
    for (int k = 0; k < 21; ++k) w[k] = vwc[k];

    const int cg = tid & 15;               // cols x0+8cg..x0+8cg+7
    const int rg = tid >> 4;               // rows y0+4rg..y0+4rg+3
    unsigned short* dst = a3 + (size_t)bc * (HH * WW)
                        + (size_t)(y0 + rg * 4) * WW + x0 + cg * 8;

    #pragma unroll 1
    for (int i = 0; i < 4; ++i) {
        float s0 = 0.f, s1 = 0.f, s2 = 0.f, s3 = 0.f;
        float s4 = 0.f, s5 = 0.f, s6 = 0.f, s7 = 0.f;
        #pragma unroll
        for (int k = 0; k < 21; ++k) {
            uint4 u = *reinterpret_cast<const uint4*>(&lds[rg * 4 + i + k][cg * 8]);
            float wk = w[k];
            s0 = fmaf(wk, bflo(u.x), s0); s1 = fmaf(wk, bfhi(u.x), s1);
            s2 = fmaf(wk, bflo(u.y), s2); s3 = fmaf(wk, bfhi(u.y), s3);
            s4 = fmaf(wk, bflo(u.z), s4); s5 = fmaf(wk, bfhi(u.z), s5);
            s6 = fmaf(wk, bflo(u.w), s6); s7 = fmaf(wk, bfhi(u.w), s7);
        }
        uint4 o;
        o.x = (unsigned int)f2bf(s0) | ((unsigned int)f2bf(s1) << 16);
        o.y = (unsigned int)f2bf(s2) | ((unsigned int)f2bf(s3) << 16);
        o.z = (unsigned int)f2bf(s4) | ((unsigned int)f2bf(s5) << 16);
        o.w = (unsigned int)f2bf(s6) | ((unsigned int)f2bf(s7) << 16);
        *reinterpret_cast<uint4*>(dst + (size_t)i * WW) = o;
    }
}

// ---------------------------------------------------------------------------
// K2b: 1x1 pointwise (64x64) + BN + sigmoid gate.
// SPILL FIX (round-3 counters: VGPR_Count=44 < 64 accs -> scratch thrash):
// 512 threads, 8 waves; wave w owns 8 output channels -> acc[32]/thread.
// __launch_bounds__(512,4) caps VGPR at 128 so accs stay in registers.
// Per-output FMA order over ci identical to round 3 -> bitwise-same result.
// ---------------------------------------------------------------------------
__global__ __launch_bounds__(512, 4) void k2b_pw(
        const unsigned short* __restrict__ a3, const float* __restrict__ x,
        const float* __restrict__ pw, const float* __restrict__ gamma,
        const float* __restrict__ beta, const float* __restrict__ mean,
        const float* __restrict__ var, float* __restrict__ out) {
    const int y   = blockIdx.x;
    const int b   = blockIdx.y;
    const int tid = threadIdx.x;

    __shared__ unsigned short a3s[64][256];   // 32 KB

    const unsigned short* abase = a3 + ((size_t)b * CC * HH + y) * WW;
    for (int i = tid; i < 64 * 64; i += 512) {
        int ci = i >> 6, q = (i & 63) << 2;
        ushort4 v = *reinterpret_cast<const ushort4*>(abase + (size_t)ci * HH * WW + q);
        *reinterpret_cast<ushort4*>(&a3s[ci][q]) = v;
    }
    __syncthreads();

    const int wu = __builtin_amdgcn_readfirstlane(tid >> 6);  // wave-uniform, 0..7
    const int l  = tid & 63;

    float acc[32];
    #pragma unroll
    for (int i = 0; i < 32; ++i) acc[i] = 0.f;

    const float* wbase = pw + (size_t)(wu * 8) * 64;   // 8 co per wave

    #pragma unroll
    for (int ch = 0; ch < 16; ++ch) {
        ushort4 q0 = *reinterpret_cast<const ushort4*>(&a3s[4 * ch + 0][l << 2]);
        ushort4 q1 = *reinterpret_cast<const ushort4*>(&a3s[4 * ch + 1][l << 2]);
        ushort4 q2 = *reinterpret_cast<const ushort4*>(&a3s[4 * ch + 2][l << 2]);
        ushort4 q3 = *reinterpret_cast<const ushort4*>(&a3s[4 * ch + 3][l << 2]);
        float p0x = bf2f(q0.x), p0y = bf2f(q0.y), p0z = bf2f(q0.z), p0w = bf2f(q0.w);
        float p1x = bf2f(q1.x), p1y = bf2f(q1.y), p1z = bf2f(q1.z), p1w = bf2f(q1.w);
        float p2x = bf2f(q2.x), p2y = bf2f(q2.y), p2z = bf2f(q2.z), p2w = bf2f(q2.w);
        float p3x = bf2f(q3.x), p3y = bf2f(q3.y), p3z = bf2f(q3.z), p3w = bf2f(q3.w);
        #pragma unroll
        for (int j = 0; j < 8; ++j) {
            float4 w4 = *reinterpret_cast<const float4*>(wbase + (size_t)j * 64 + 4 * ch);
            acc[j * 4 + 0] = fmaf(w4.x, p0x, acc[j * 4 + 0]);
            acc[j * 4 + 0] = fmaf(w4.y, p1x, acc[j * 4 + 0]);
            acc[j * 4 + 0] = fmaf(w4.z, p2x, acc[j * 4 + 0]);
            acc[j * 4 + 0] = fmaf(w4.w, p3x, acc[j * 4 + 0]);
            acc[j * 4 + 1] = fmaf(w4.x, p0y, acc[j * 4 + 1]);
            acc[j * 4 + 1] = fmaf(w4.y, p1y, acc[j * 4 + 1]);
            acc[j * 4 + 1] = fmaf(w4.z, p2y, acc[j * 4 + 1]);
            acc[j * 4 + 1] = fmaf(w4.w, p3y, acc[j * 4 + 1]);
            acc[j * 4 + 2] = fmaf(w4.x, p0z, acc[j * 4 + 2]);
            acc[j * 4 + 2] = fmaf(w4.y, p1z, acc[j * 4 + 2]);
            acc[j * 4 + 2] = fmaf(w4.z, p2z, acc[j * 4 + 2]);
            acc[j * 4 + 2] = fmaf(w4.w, p3z, acc[j * 4 + 2]);
            acc[j * 4 + 3] = fmaf(w4.x, p0w, acc[j * 4 + 3]);
            acc[j * 4 + 3] = fmaf(w4.y, p1w, acc[j * 4 + 3]);
            acc[j * 4 + 3] = fmaf(w4.z, p2w, acc[j * 4 + 3]);
            acc[j * 4 + 3] = fmaf(w4.w, p3w, acc[j * 4 + 3]);
        }
    }

    #pragma unroll
    for (int j = 0; j < 8; ++j) {
        int co = wu * 8 + j;
        float inv = gamma[co] * rsqrtf(var[co] + 1e-5f);
        float sh  = beta[co] - mean[co] * inv;
        size_t off = (((size_t)b * CC + co) * HH + y) * WW + (l << 2);
        float4 xv = *reinterpret_cast<const float4*>(x + off);
        float4 r;
        float a;
        a = acc[j * 4 + 0] * inv + sh; r.x = xv.x / (1.f + __expf(-a));
        a = acc[j * 4 + 1] * inv + sh; r.y = xv.y / (1.f + __expf(-a));
        a = acc[j * 4 + 2] * inv + sh; r.z = xv.z / (1.f + __expf(-a));
        a = acc[j * 4 + 3] * inv + sh; r.w = xv.w / (1.f + __expf(-a));
        *reinterpret_cast<float4*>(out + off) = r;
    }
}

extern "C" void kernel_launch(void* const* d_in, const int* in_sizes, int n_in,
                              void* d_out, int out_size, void* d_ws, size_t ws_size,
                              hipStream_t stream) {
    const float* x     = (const float*)d_in[0];
    const float* lw    = (const float*)d_in[1];
    const float* hw    = (const float*)d_in[2];
    const float* vw    = (const float*)d_in[3];
    const float* pw    = (const float*)d_in[4];
    const float* gamma = (const float*)d_in[5];
    const float* beta  = (const float*)d_in[6];
    const float* mean  = (const float*)d_in[7];
    const float* var   = (const float*)d_in[8];
    float* out = (float*)d_out;

    // ws: attn2 (bf16) + attn3 (bf16) = 2 * 64 MiB = 128 MiB
    unsigned short* ws1 = (unsigned short*)d_ws;
    unsigned short* ws2 = ws1 + (size_t)BB * CC * HH * WW;

    k1_local_h<<<dim3(HH / 32, BB * CC), 512, 0, stream>>>(x, lw, hw, ws1);
    k2a_v<<<dim3(8, BB * CC), 256, 0, stream>>>(ws1, vw, ws2);
    k2b_pw<<<dim3(HH, BB), 512, 0, stream>>>(ws2, x, pw, gamma, beta, mean, var, out);
}